// Round 10
// baseline (193.901 us; speedup 1.0000x reference)
//
#include <hip/hip_runtime.h>
#include <stdint.h>

#define NN 16384
#define DD 128
#define KT 64        // k-tile rows per window
#define QB 128       // q rows per block (4 waves x 32)
#define KSTR 144     // K LDS row stride (128 data + 16 pad)
#define VSTR 72      // V^T LDS row stride (64 data + 8 pad)
#define KBYTES 9216  // 64 * 144
#define VBYTES 9216  // 128 * 72

typedef float f32x16 __attribute__((ext_vector_type(16)));
typedef int i32x8 __attribute__((ext_vector_type(8)));
typedef long long i64;

using gv = __attribute__((address_space(1))) const void;
using lv = __attribute__((address_space(3))) void;

__device__ __forceinline__ i32x8 mk8(uint4 a, uint4 b) {
  i32x8 r;
  r[0] = a.x; r[1] = a.y; r[2] = a.z; r[3] = a.w;
  r[4] = b.x; r[5] = b.y; r[6] = b.z; r[7] = b.w;
  return r;
}

#define MFMA64(A, B, C) \
  __builtin_amdgcn_mfma_scale_f32_32x32x64_f8f6f4((A), (B), (C), 0, 0, 0, 0x7F7F7F7F, 0, 0x7F7F7F7F)
#define LD16(p) (*reinterpret_cast<const uint4*>(p))

// K-prep (fused k_norm + k_transpose): one pass over x.
//  - nx: fp8 row-normalized rows, scaled by sqrt(log2 e) (softmax = 2^s)
//  - xT: fp8 [D][N] transpose of raw x
__global__ void k_prep(const float* __restrict__ x, uint8_t* __restrict__ nx,
                       uint8_t* __restrict__ xT) {
  __shared__ uint8_t tile[64 * 132];  // 64 rows x 128 fp8 cols, stride 132
  const int n0 = blockIdx.x * 64;
  const int t = threadIdx.x;
  const int r = t >> 2;   // row 0..63
  const int qd = t & 3;   // 32-col quarter

  const float* xr = x + (size_t)(n0 + r) * DD + qd * 32;
  float4 v[8];
  float ss = 0.f;
#pragma unroll
  for (int j = 0; j < 8; ++j) {
    v[j] = *reinterpret_cast<const float4*>(xr + 4 * j);
    ss += v[j].x * v[j].x + v[j].y * v[j].y + v[j].z * v[j].z + v[j].w * v[j].w;
  }
  ss += __shfl_xor(ss, 1);
  ss += __shfl_xor(ss, 2);
  const float rn = 1.2011224087f / fmaxf(sqrtf(ss), 1e-12f);  // sqrt(log2 e)/|x|

  uint32_t nb[8];
#pragma unroll
  for (int j = 0; j < 8; ++j) {
    // scaled (for nx)
    uint32_t w = (uint32_t)__builtin_amdgcn_cvt_pk_fp8_f32(v[j].x * rn, v[j].y * rn, 0, false);
    w = (uint32_t)__builtin_amdgcn_cvt_pk_fp8_f32(v[j].z * rn, v[j].w * rn, (int)w, true);
    nb[j] = w;
    // raw (for xT) -> LDS tile
    uint32_t u = (uint32_t)__builtin_amdgcn_cvt_pk_fp8_f32(v[j].x, v[j].y, 0, false);
    u = (uint32_t)__builtin_amdgcn_cvt_pk_fp8_f32(v[j].z, v[j].w, (int)u, true);
    *reinterpret_cast<uint32_t*>(&tile[r * 132 + qd * 32 + 4 * j]) = u;
  }
  uint4 o0 = {nb[0], nb[1], nb[2], nb[3]};
  uint4 o1 = {nb[4], nb[5], nb[6], nb[7]};
  uint8_t* nrow = nx + (size_t)(n0 + r) * DD + qd * 32;
  *reinterpret_cast<uint4*>(nrow) = o0;
  *reinterpret_cast<uint4*>(nrow + 16) = o1;

  __syncthreads();
#pragma unroll
  for (int e = 0; e < 8; ++e) {
    const int idx = e * 256 + t;
    const int d = idx >> 4, n4 = (idx & 15) << 2;
    uint32_t w = (uint32_t)tile[(n4 + 0) * 132 + d];
    w |= (uint32_t)tile[(n4 + 1) * 132 + d] << 8;
    w |= (uint32_t)tile[(n4 + 2) * 132 + d] << 16;
    w |= (uint32_t)tile[(n4 + 3) * 132 + d] << 24;
    *reinterpret_cast<uint32_t*>(xT + (size_t)d * NN + n0 + n4) = w;
  }
}

#define SMPACK(sv_, W_)                                                   \
  {                                                                       \
    _Pragma("unroll") for (int g = 0; g < 4; ++g) {                       \
      float e0_, e1_, e2_, e3_;                                           \
      asm("v_exp_f32 %0, %1" : "=v"(e0_) : "v"(sv_[4 * g + 0]));          \
      asm("v_exp_f32 %0, %1" : "=v"(e1_) : "v"(sv_[4 * g + 1]));          \
      asm("v_exp_f32 %0, %1" : "=v"(e2_) : "v"(sv_[4 * g + 2]));          \
      asm("v_exp_f32 %0, %1" : "=v"(e3_) : "v"(sv_[4 * g + 3]));          \
      lsum += (e0_ + e1_) + (e2_ + e3_);                                  \
      uint32_t w_ = (uint32_t)__builtin_amdgcn_cvt_pk_fp8_f32(e0_, e1_, 0, false); \
      w_ = (uint32_t)__builtin_amdgcn_cvt_pk_fp8_f32(e2_, e3_, (int)w_, true);     \
      W_[g] = w_;                                                         \
    }                                                                     \
  }

// K2: flash attention — R4 structure (proven 89% busy-packed): 4 waves x 32
// q-rows; QK^T swapped, K=32 non-scaled fp8 MFMA fed by b64 LDS reads;
// in-register softmax; P packed to ONE K=64 A-frag (cvt_pk_fp8 + 4x
// permlane32_swap) feeding 4 MX-scaled 32x32x64 PV MFMAs (-17% MFMA work).
// K/V staged via global_load_lds into padded LDS (144/72); 2-buf;
// per-wave vmcnt(0) before the barrier; per-block k-start rotation.
template <int NSPLIT>
__global__ __launch_bounds__(256, 4) void k_attn(
    const uint8_t* __restrict__ nx, const uint8_t* __restrict__ xT,
    float* __restrict__ Op, float* __restrict__ Lp) {
  __shared__ alignas(16) uint8_t Kb[2][KBYTES];
  __shared__ alignas(16) uint8_t Vb[2][VBYTES];

  const int tid = threadIdx.x;
  const int wave = tid >> 6;
  const int lane = tid & 63;
  const int rl = lane & 31;
  const int hi = lane >> 5;

  // XCD-grouped: split s lives on its XCD group -> K/V slice L2-resident.
  const int id = blockIdx.x;
  constexpr int gs = 8 / NSPLIT;
  const int split = (id & 7) / gs;
  const int qblock = (id >> 3) * gs + (id & (gs - 1));

  constexpr int nt = 256 / NSPLIT;   // power of 2 for NSPLIT in {2,4,8}
  const int t0s = split * nt;
  const int pst = (id >> 3) & (nt - 1);   // k-start rotation (sum-invariant)
  const int qw = qblock * QB + wave * 32;

  // ---- staging: waves 0,1 -> K units; waves 2,3 -> V units ----
  const int sw = wave >> 1;
  const int j0 = (wave & 1) * 5;
  const int cnt = (wave & 1) ? 4 : 5;
  uint32_t soff[5];
#pragma unroll
  for (int i = 0; i < 5; ++i) {
    const int j = j0 + i;
    const int t16 = j * 64 + lane;
    if (sw == 0) {
      soff[i] = (uint32_t)((t16 / 9) * DD + (t16 % 9) * 16);
    } else {
      const int d = (2 * t16) / 9;
      const int c0 = t16 * 16 - d * VSTR;
      soff[i] = (uint32_t)(d * NN + c0 + (c0 >= 64 ? (NN - VSTR) : 0));
    }
  }

  auto stage = [&](int tt, int buf) {
    const int k0 = tt * KT;
    const uint8_t* basep = (sw == 0) ? (nx + (size_t)k0 * DD) : (xT + k0);
    uint8_t* ldsb = (sw == 0) ? &Kb[buf][0] : &Vb[buf][0];
#pragma unroll
    for (int i = 0; i < 5; ++i)
      if (i < cnt)
        __builtin_amdgcn_global_load_lds((gv*)(basep + soff[i]),
            (lv*)(ldsb + (j0 + i) * 1024), 16, 0, 0);
  };

  // Q B-frags (fp8, K=32 ops): col q = l&31, d = dc*16 + 8*hi .. +8
  i64 q8[8];
#pragma unroll
  for (int dc = 0; dc < 8; ++dc)
    q8[dc] = *reinterpret_cast<const i64*>(nx + (size_t)(qw + rl) * DD + dc * 16 + 8 * hi);

  f32x16 o[4];
#pragma unroll
  for (int dt = 0; dt < 4; ++dt)
#pragma unroll
    for (int r = 0; r < 16; ++r) o[dt][r] = 0.f;
  float lsum = 0.f;

  stage(t0s + pst, 0);

  for (int t = 0; t < nt; ++t) {
    const int buf = t & 1;
    __builtin_amdgcn_sched_barrier(0);
    asm volatile("s_waitcnt vmcnt(0)" ::: "memory");  // own stage(t) landed
    __builtin_amdgcn_sched_barrier(0);
    __builtin_amdgcn_s_barrier();                     // tile t published
    __builtin_amdgcn_sched_barrier(0);
    if (t + 1 < nt) stage(t0s + ((t + 1 + pst) & (nt - 1)), buf ^ 1);

    const uint8_t* kb = &Kb[buf][0];
    const uint8_t* vb = &Vb[buf][0];

    // ---- QK^T (swapped): S^T[k][q] per 32-row k-subtile, K=32 MFMA ----
    uint32_t W0[4], W1[4];
#pragma unroll
    for (int kt = 0; kt < 2; ++kt) {
      const uint8_t* kbb = kb + kt * 32 * KSTR + rl * KSTR + 8 * hi;
      f32x16 s = {};
      __builtin_amdgcn_s_setprio(1);
#pragma unroll
      for (int dc = 0; dc < 8; ++dc) {
        const i64 ka = *reinterpret_cast<const i64*>(kbb + dc * 16);
        s = __builtin_amdgcn_mfma_f32_32x32x16_fp8_fp8(ka, q8[dc], s, 0, 0, 0);
      }
      __builtin_amdgcn_s_setprio(0);
      // p = 2^s (pre-scaled by log2 e; |s|<=1.45 -> no max tracking);
      // W[kt][g] packs k {8g+4hi+0..3} (+32kt) from s[4g+0..3]
      if (kt == 0) { SMPACK(s, W0); } else { SMPACK(s, W1); }
    }
    // after swap: frag bytes linear k = 32*hi + b  (one K=64 A-frag)
#pragma unroll
    for (int g = 0; g < 4; ++g)
      asm("v_permlane32_swap_b32 %0, %1" : "+v"(W0[g]), "+v"(W1[g]));
    i32x8 pa;
    pa[0] = (int)W0[0]; pa[1] = (int)W1[0]; pa[2] = (int)W0[1]; pa[3] = (int)W1[1];
    pa[4] = (int)W0[2]; pa[5] = (int)W1[2]; pa[6] = (int)W0[3]; pa[7] = (int)W1[3];

    // ---- PV: O[q][d] += P * V, one K=64 scaled MFMA per d-tile ----
    __builtin_amdgcn_s_setprio(1);
#pragma unroll
    for (int dt = 0; dt < 4; ++dt) {
      const uint8_t* vp = vb + (dt * 32 + rl) * VSTR + 32 * hi;
      const i32x8 vf = mk8(LD16(vp), LD16(vp + 16));
      o[dt] = MFMA64(pa, vf, o[dt]);
    }
    __builtin_amdgcn_s_setprio(0);
  }

  // L[q]: lanes l and l+32 hold complementary k-subsets of the same q
  const float lt = lsum + __shfl_xor(lsum, 32);
  if (hi == 0) Lp[(size_t)split * NN + qw + rl] = lt;

  float* Ob = Op + (size_t)split * NN * DD;
#pragma unroll
  for (int dt = 0; dt < 4; ++dt)
#pragma unroll
    for (int r = 0; r < 16; ++r) {
      const int q = (r & 3) + 8 * (r >> 2) + 4 * hi;
      Ob[(size_t)(qw + q) * DD + dt * 32 + rl] = o[dt][r];
    }
}

// K3: combine splits, y = 1.5x - 0.5*(O/L), LayerNorm over D, write fp32 out.
__global__ void k_final(const float* __restrict__ x, const float* __restrict__ gamma,
                        const float* __restrict__ beta, const float* __restrict__ Op,
                        const float* __restrict__ Lp, float* __restrict__ out, int nsplit) {
  const int wave = threadIdx.x >> 6, lane = threadIdx.x & 63;
  const int row = blockIdx.x * 4 + wave;
  float o0 = 0.f, o1 = 0.f, lt = 0.f;
  for (int s = 0; s < nsplit; ++s) {
    const float2 v = *reinterpret_cast<const float2*>(
        Op + (size_t)s * NN * DD + (size_t)row * DD + 2 * lane);
    o0 += v.x;
    o1 += v.y;
    lt += Lp[(size_t)s * NN + row];
  }
  const float inv = 1.0f / lt;
  const float2 xv = *reinterpret_cast<const float2*>(x + (size_t)row * DD + 2 * lane);
  float y0 = 1.5f * xv.x - 0.5f * o0 * inv;
  float y1 = 1.5f * xv.y - 0.5f * o1 * inv;
  float sum = y0 + y1;
#pragma unroll
  for (int m = 1; m < 64; m <<= 1) sum += __shfl_xor(sum, m);
  const float mu = sum * (1.0f / 128.0f);
  const float d0 = y0 - mu, d1 = y1 - mu;
  float vs = d0 * d0 + d1 * d1;
#pragma unroll
  for (int m = 1; m < 64; m <<= 1) vs += __shfl_xor(vs, m);
  const float rs = rsqrtf(vs * (1.0f / 128.0f) + 1e-5f);
  const float2 g = *reinterpret_cast<const float2*>(gamma + 2 * lane);
  const float2 b = *reinterpret_cast<const float2*>(beta + 2 * lane);
  float2 ov;
  ov.x = d0 * rs * g.x + b.x;
  ov.y = d1 * rs * g.y + b.y;
  *reinterpret_cast<float2*>(out + (size_t)row * DD + 2 * lane) = ov;
}

extern "C" void kernel_launch(void* const* d_in, const int* in_sizes, int n_in,
                              void* d_out, int out_size, void* d_ws, size_t ws_size,
                              hipStream_t stream) {
  const float* x = (const float*)d_in[0];
  const float* gamma = (const float*)d_in[1];
  const float* beta = (const float*)d_in[2];
  float* out = (float*)d_out;
  char* ws = (char*)d_ws;

  uint8_t* nx = (uint8_t*)ws;                           // 2 MiB fp8 [N][D], scaled
  uint8_t* xT = (uint8_t*)(ws + (size_t)NN * DD);       // 2 MiB fp8 [D][N]
  const size_t base = (size_t)2 * NN * DD;
  const size_t per = (size_t)NN * DD * 4 + (size_t)NN * 4;  // per-split O + L

  int nsplit = 2;
  if (ws_size >= base + 8 * per) nsplit = 8;
  else if (ws_size >= base + 4 * per) nsplit = 4;

  float* Op = (float*)(ws + base);
  float* Lp = (float*)(ws + base + (size_t)nsplit * NN * DD * 4);

  k_prep<<<NN / 64, 256, 0, stream>>>(x, nx, xT);
  if (nsplit == 8)
    k_attn<8><<<dim3(128 * 8), 256, 0, stream>>>(nx, xT, Op, Lp);
  else if (nsplit == 4)
    k_attn<4><<<dim3(128 * 4), 256, 0, stream>>>(nx, xT, Op, Lp);
  else
    k_attn<2><<<dim3(128 * 2), 256, 0, stream>>>(nx, xT, Op, Lp);
  k_final<<<NN / 4, 256, 0, stream>>>(x, gamma, beta, Op, Lp, out, nsplit);
}

// Round 11
// 133.737 us; speedup vs baseline: 1.4499x; 1.4499x over previous
//
#include <hip/hip_runtime.h>
#include <stdint.h>

#define NN 16384
#define DD 128
#define KT 64        // k-tile rows
#define QB 128       // q rows per block (4 waves x 32)
#define KSTR 144     // K LDS row stride (128 data + 16 pad)
#define VSTR 72      // V^T LDS row stride (64 data + 8 pad)
#define KBYTES 9216  // 64 * 144
#define VBYTES 9216  // 128 * 72

typedef float f32x16 __attribute__((ext_vector_type(16)));
typedef long long i64;

using gv = __attribute__((address_space(1))) const void;
using lv = __attribute__((address_space(3))) void;

#define LD16(p) (*reinterpret_cast<const uint4*>(p))

__device__ __forceinline__ i64 mki64(uint32_t a, uint32_t b) {
  uint2 u = {a, b};
  return __builtin_bit_cast(i64, u);
}

// fast 2^s for s in [-1.5, 1.5]: Schraudolph bit-trick, minimax mantissa bias.
// 2 full-rate VALU ops instead of 1 quarter-rate v_exp_f32. Rel err <= +-3.6%.
#define EXP2A(s_, p_)                                                   \
  {                                                                     \
    const float t_ = __builtin_fmaf((s_), 8388608.0f, 1065062131.0f);   \
    const int u_ = (int)t_;                                             \
    p_ = __builtin_bit_cast(float, u_);                                 \
  }

// K-prep (fused norm + transpose, one pass over x):
//  - nx: fp8 e4m3 row-normalized rows scaled by sqrt(log2 e) (softmax = 2^s)
//  - xT: fp8 [D][N] transpose of raw x
__global__ void k_prep(const float* __restrict__ x, uint8_t* __restrict__ nx,
                       uint8_t* __restrict__ xT) {
  __shared__ uint8_t tile[64 * 132];
  const int n0 = blockIdx.x * 64;
  const int t = threadIdx.x;
  const int r = t >> 2;
  const int qd = t & 3;

  const float* xr = x + (size_t)(n0 + r) * DD + qd * 32;
  float4 v[8];
  float ss = 0.f;
#pragma unroll
  for (int j = 0; j < 8; ++j) {
    v[j] = *reinterpret_cast<const float4*>(xr + 4 * j);
    ss += v[j].x * v[j].x + v[j].y * v[j].y + v[j].z * v[j].z + v[j].w * v[j].w;
  }
  ss += __shfl_xor(ss, 1);
  ss += __shfl_xor(ss, 2);
  const float rn = 1.2011224087f / fmaxf(sqrtf(ss), 1e-12f);  // sqrt(log2 e)/|x|

  uint32_t nb[8];
#pragma unroll
  for (int j = 0; j < 8; ++j) {
    uint32_t w = (uint32_t)__builtin_amdgcn_cvt_pk_fp8_f32(v[j].x * rn, v[j].y * rn, 0, false);
    w = (uint32_t)__builtin_amdgcn_cvt_pk_fp8_f32(v[j].z * rn, v[j].w * rn, (int)w, true);
    nb[j] = w;
    uint32_t u = (uint32_t)__builtin_amdgcn_cvt_pk_fp8_f32(v[j].x, v[j].y, 0, false);
    u = (uint32_t)__builtin_amdgcn_cvt_pk_fp8_f32(v[j].z, v[j].w, (int)u, true);
    *reinterpret_cast<uint32_t*>(&tile[r * 132 + qd * 32 + 4 * j]) = u;
  }
  uint4 o0 = {nb[0], nb[1], nb[2], nb[3]};
  uint4 o1 = {nb[4], nb[5], nb[6], nb[7]};
  uint8_t* nrow = nx + (size_t)(n0 + r) * DD + qd * 32;
  *reinterpret_cast<uint4*>(nrow) = o0;
  *reinterpret_cast<uint4*>(nrow + 16) = o1;

  __syncthreads();
#pragma unroll
  for (int e = 0; e < 8; ++e) {
    const int idx = e * 256 + t;
    const int d = idx >> 4, n4 = (idx & 15) << 2;
    uint32_t w = (uint32_t)tile[(n4 + 0) * 132 + d];
    w |= (uint32_t)tile[(n4 + 1) * 132 + d] << 8;
    w |= (uint32_t)tile[(n4 + 2) * 132 + d] << 16;
    w |= (uint32_t)tile[(n4 + 3) * 132 + d] << 24;
    *reinterpret_cast<uint32_t*>(xT + (size_t)d * NN + n0 + n4) = w;
  }
}

// K2: flash attention — R4 structure exactly (proven 89% busy-packed):
// 4 waves x 32 q-rows, non-scaled fp8 32x32x16 MFMA throughout, swapped
// QK^T, in-register softmax (bit-trick 2^s), P -> fp8 A-frags via
// cvt_pk_fp8 + permlane32_swap. K/V staged via global_load_lds into padded
// LDS (144/72); 2-buffer; per-wave vmcnt(0) before barrier; no rotation
// (co-resident blocks share staging addresses -> L1 hits). QK LDS reads
// are b128 (two K=16 frags per read; Q d-map matched pairwise).
template <int NSPLIT>
__global__ __launch_bounds__(256, 4) void k_attn(
    const uint8_t* __restrict__ nx, const uint8_t* __restrict__ xT,
    float* __restrict__ Op, float* __restrict__ Lp) {
  __shared__ alignas(16) uint8_t Kb[2][KBYTES];
  __shared__ alignas(16) uint8_t Vb[2][VBYTES];

  const int tid = threadIdx.x;
  const int wave = tid >> 6;
  const int lane = tid & 63;
  const int rl = lane & 31;
  const int hi = lane >> 5;

  // XCD-grouped: split s lives on its XCD group -> K/V slice L2-resident.
  const int id = blockIdx.x;
  constexpr int gs = 8 / NSPLIT;
  const int split = (id & 7) / gs;
  const int qblock = (id >> 3) * gs + (id & (gs - 1));

  constexpr int nt = 256 / NSPLIT;
  const int t0s = split * nt;
  const int qw = qblock * QB + wave * 32;

  // ---- staging: waves 0,1 -> K units; waves 2,3 -> V units ----
  const int sw = wave >> 1;
  const int j0 = (wave & 1) * 5;
  const int cnt = (wave & 1) ? 4 : 5;
  uint32_t soff[5];
#pragma unroll
  for (int i = 0; i < 5; ++i) {
    const int j = j0 + i;
    const int t16 = j * 64 + lane;
    if (sw == 0) {
      soff[i] = (uint32_t)((t16 / 9) * DD + (t16 % 9) * 16);
    } else {
      const int d = (2 * t16) / 9;
      const int c0 = t16 * 16 - d * VSTR;
      soff[i] = (uint32_t)(d * NN + c0 + (c0 >= 64 ? (NN - VSTR) : 0));
    }
  }

  auto stage = [&](int tt, int buf) {
    const int k0 = tt * KT;
    const uint8_t* basep = (sw == 0) ? (nx + (size_t)k0 * DD) : (xT + k0);
    uint8_t* ldsb = (sw == 0) ? &Kb[buf][0] : &Vb[buf][0];
#pragma unroll
    for (int i = 0; i < 5; ++i)
      if (i < cnt)
        __builtin_amdgcn_global_load_lds((gv*)(basep + soff[i]),
            (lv*)(ldsb + (j0 + i) * 1024), 16, 0, 0);
  };

  // Q B-frags (fp8, K=16 ops), pairwise d-map: frag pair j covers
  // d = 32j + 16*hi + byte (A-side K reads use the identical map).
  const uint8_t* qrow = nx + (size_t)(qw + rl) * DD + 16 * hi;
  i64 q8[8];
#pragma unroll
  for (int j = 0; j < 4; ++j) {
    const uint4 qa = LD16(qrow + 32 * j);
    q8[2 * j] = mki64(qa.x, qa.y);
    q8[2 * j + 1] = mki64(qa.z, qa.w);
  }

  f32x16 o[4];
#pragma unroll
  for (int dt = 0; dt < 4; ++dt)
#pragma unroll
    for (int r = 0; r < 16; ++r) o[dt][r] = 0.f;
  float lsum = 0.f;

  stage(t0s, 0);

  for (int t = 0; t < nt; ++t) {
    const int buf = t & 1;
    __builtin_amdgcn_sched_barrier(0);
    asm volatile("s_waitcnt vmcnt(0)" ::: "memory");  // own stage(t) landed
    __builtin_amdgcn_sched_barrier(0);
    __builtin_amdgcn_s_barrier();                     // tile t published
    __builtin_amdgcn_sched_barrier(0);
    if (t + 1 < nt) stage(t0s + t + 1, buf ^ 1);

    const uint8_t* kb = &Kb[buf][0];
    const uint8_t* vb = &Vb[buf][0];
    i64 pa[4];

    // ---- per 32-row k-subtile: QK^T (b128 K reads) + softmax + pack ----
#pragma unroll
    for (int kt = 0; kt < 2; ++kt) {
      const uint8_t* kbb = kb + kt * 32 * KSTR + rl * KSTR + 16 * hi;
      f32x16 s;
#pragma unroll
      for (int r = 0; r < 16; ++r) s[r] = 0.f;
      __builtin_amdgcn_s_setprio(1);
#pragma unroll
      for (int j = 0; j < 4; ++j) {
        const uint4 kw = LD16(kbb + 32 * j);
        const i64 ka0 = mki64(kw.x, kw.y);
        const i64 ka1 = mki64(kw.z, kw.w);
        s = __builtin_amdgcn_mfma_f32_32x32x16_fp8_fp8(ka0, q8[2 * j], s, 0, 0, 0);
        s = __builtin_amdgcn_mfma_f32_32x32x16_fp8_fp8(ka1, q8[2 * j + 1], s, 0, 0, 0);
      }
      __builtin_amdgcn_s_setprio(0);
      // softmax: p = 2^s (pre-scaled by log2 e; |s|<=1.45, no max tracking)
      // lane holds P[q=l&31][k_local=(r&3)+8*(r>>2)+4*hi+32*kt]
#pragma unroll
      for (int kc = 0; kc < 2; ++kc) {
        float e[8];
#pragma unroll
        for (int jj = 0; jj < 8; ++jj) {
          EXP2A(s[8 * kc + jj], e[jj]);
          lsum += e[jj];
        }
        uint32_t wlo = (uint32_t)__builtin_amdgcn_cvt_pk_fp8_f32(e[0], e[1], 0, false);
        wlo = (uint32_t)__builtin_amdgcn_cvt_pk_fp8_f32(e[2], e[3], (int)wlo, true);
        uint32_t whi = (uint32_t)__builtin_amdgcn_cvt_pk_fp8_f32(e[4], e[5], 0, false);
        whi = (uint32_t)__builtin_amdgcn_cvt_pk_fp8_f32(e[6], e[7], (int)whi, true);
        asm("v_permlane32_swap_b32 %0, %1" : "+v"(wlo), "+v"(whi));
        const uint2 pd = {wlo, whi};
        pa[kt * 2 + kc] = __builtin_bit_cast(i64, pd);
      }
    }

    // ---- PV: O[q][d] += P * V ----
    __builtin_amdgcn_s_setprio(1);
#pragma unroll
    for (int c4 = 0; c4 < 4; ++c4) {
      const int cb = c4 * 16 + 8 * hi;
#pragma unroll
      for (int dt = 0; dt < 4; ++dt) {
        const i64 vf = __builtin_bit_cast(i64,
            *reinterpret_cast<const uint2*>(vb + (dt * 32 + rl) * VSTR + cb));
        o[dt] = __builtin_amdgcn_mfma_f32_32x32x16_fp8_fp8(pa[c4], vf, o[dt], 0, 0, 0);
      }
    }
    __builtin_amdgcn_s_setprio(0);
  }

  // L[q]: lanes l and l+32 hold complementary k-subsets of the same q
  const float lt = lsum + __shfl_xor(lsum, 32);
  if (hi == 0) Lp[(size_t)split * NN + qw + rl] = lt;

  float* Ob = Op + (size_t)split * NN * DD;
#pragma unroll
  for (int dt = 0; dt < 4; ++dt)
#pragma unroll
    for (int r = 0; r < 16; ++r) {
      const int q = (r & 3) + 8 * (r >> 2) + 4 * hi;
      Ob[(size_t)(qw + q) * DD + dt * 32 + rl] = o[dt][r];
    }
}

// K3: combine splits, y = 1.5x - 0.5*(O/L), LayerNorm over D, write fp32 out.
__global__ void k_final(const float* __restrict__ x, const float* __restrict__ gamma,
                        const float* __restrict__ beta, const float* __restrict__ Op,
                        const float* __restrict__ Lp, float* __restrict__ out, int nsplit) {
  const int wave = threadIdx.x >> 6, lane = threadIdx.x & 63;
  const int row = blockIdx.x * 4 + wave;
  float o0 = 0.f, o1 = 0.f, lt = 0.f;
  for (int s = 0; s < nsplit; ++s) {
    const float2 v = *reinterpret_cast<const float2*>(
        Op + (size_t)s * NN * DD + (size_t)row * DD + 2 * lane);
    o0 += v.x;
    o1 += v.y;
    lt += Lp[(size_t)s * NN + row];
  }
  const float inv = 1.0f / lt;
  const float2 xv = *reinterpret_cast<const float2*>(x + (size_t)row * DD + 2 * lane);
  float y0 = 1.5f * xv.x - 0.5f * o0 * inv;
  float y1 = 1.5f * xv.y - 0.5f * o1 * inv;
  float sum = y0 + y1;
#pragma unroll
  for (int m = 1; m < 64; m <<= 1) sum += __shfl_xor(sum, m);
  const float mu = sum * (1.0f / 128.0f);
  const float d0 = y0 - mu, d1 = y1 - mu;
  float vs = d0 * d0 + d1 * d1;
#pragma unroll
  for (int m = 1; m < 64; m <<= 1) vs += __shfl_xor(vs, m);
  const float rs = rsqrtf(vs * (1.0f / 128.0f) + 1e-5f);
  const float2 g = *reinterpret_cast<const float2*>(gamma + 2 * lane);
  const float2 b = *reinterpret_cast<const float2*>(beta + 2 * lane);
  float2 ov;
  ov.x = d0 * rs * g.x + b.x;
  ov.y = d1 * rs * g.y + b.y;
  *reinterpret_cast<float2*>(out + (size_t)row * DD + 2 * lane) = ov;
}

extern "C" void kernel_launch(void* const* d_in, const int* in_sizes, int n_in,
                              void* d_out, int out_size, void* d_ws, size_t ws_size,
                              hipStream_t stream) {
  const float* x = (const float*)d_in[0];
  const float* gamma = (const float*)d_in[1];
  const float* beta = (const float*)d_in[2];
  float* out = (float*)d_out;
  char* ws = (char*)d_ws;

  uint8_t* nx = (uint8_t*)ws;                           // 2 MiB fp8 [N][D], scaled
  uint8_t* xT = (uint8_t*)(ws + (size_t)NN * DD);       // 2 MiB fp8 [D][N]
  const size_t base = (size_t)2 * NN * DD;
  const size_t per = (size_t)NN * DD * 4 + (size_t)NN * 4;  // per-split O + L

  int nsplit = 2;
  if (ws_size >= base + 8 * per) nsplit = 8;
  else if (ws_size >= base + 4 * per) nsplit = 4;

  float* Op = (float*)(ws + base);
  float* Lp = (float*)(ws + base + (size_t)nsplit * NN * DD * 4);

  k_prep<<<NN / 64, 256, 0, stream>>>(x, nx, xT);
  if (nsplit == 8)
    k_attn<8><<<dim3(128 * 8), 256, 0, stream>>>(nx, xT, Op, Lp);
  else if (nsplit == 4)
    k_attn<4><<<dim3(128 * 4), 256, 0, stream>>>(nx, xT, Op, Lp);
  else
    k_attn<2><<<dim3(128 * 2), 256, 0, stream>>>(nx, xT, Op, Lp);
  k_final<<<NN / 4, 256, 0, stream>>>(x, gamma, beta, Op, Lp, out, nsplit);
}